// Round 7
// baseline (360.938 us; speedup 1.0000x reference)
//
#include <hip/hip_runtime.h>
#include <math.h>

#define BB 1024
#define TT 512
#define CC 53
#define BOS 1
#define EOS 2

__device__ __forceinline__ float bcast_lane(float x, int l) {
    return __uint_as_float(__builtin_amdgcn_readlane(__float_as_uint(x), l));
}

// round-to-nearest-even bf16 bits of x
__device__ __forceinline__ unsigned bf16_rne_bits(float x) {
    unsigned u = __float_as_uint(x);
    return (u + 0x7fffu + ((u >> 16) & 1u)) >> 16;
}

__global__ __launch_bounds__(64, 1) void crf_batch_kernel(
    const float* __restrict__ em,     // B,T,C
    const int*   __restrict__ tags,   // B,T
    const float* __restrict__ mask,   // B,T
    const float* __restrict__ trans,  // C,C
    float*       __restrict__ partial) // B  (partition - score)
{
    const int b = blockIdx.x;
    const int lane = threadIdx.x;             // 0..63
    const int cc = lane < CC ? lane : CC - 1; // lanes >= C mirror lane 52

    // ---- length = sum(mask[b,:]) ----
    const float* mrow = mask + (size_t)b * TT;
    float msum = 0.f;
    #pragma unroll
    for (int i = 0; i < TT / 64; ++i) msum += mrow[lane + 64 * i];
    #pragma unroll
    for (int o = 32; o > 0; o >>= 1) msum += __shfl_xor(msum, o);
    const int len = __builtin_amdgcn_readfirstlane((int)(msum + 0.5f)); // SGPR, uniform

    // ---- score (gather part), lane-parallel over t ----
    const int* trow = tags + (size_t)b * TT;
    const float* ep = em + (size_t)b * TT * CC;
    float sc = 0.f;
    for (int t = 2 + lane; t < len; t += 64) {
        int tg = trow[t];
        int tp = trow[t - 1];
        sc += ep[(size_t)t * CC + tg] + trans[tp * CC + tg];
    }
    #pragma unroll
    for (int o = 32; o > 0; o >>= 1) sc += __shfl_xor(sc, o);
    if (lane == 0) {
        int t1 = trow[1];
        sc += trans[BOS * CC + t1] + ep[1 * CC + t1];   // "first"
        int tl = trow[len];
        sc += trans[tl * CC + EOS];                      // "last" (ref: tags[:, len])
    }

    // ---- W column packed as bf16 pairs: 26 u32 regs + 1 f32 (27 total) ----
    // pk_i = [bf16(exp(trans[2i][cc])) : bf16(exp(trans[2i+1][cc]))]
    // even extract: pk & 0xffff0000 ; odd extract: pk << 16
#define PKD(i) unsigned pk##i; { \
        unsigned he = bf16_rne_bits(__expf(trans[(2*(i))     * CC + cc])); \
        unsigned ho = bf16_rne_bits(__expf(trans[(2*(i) + 1) * CC + cc])); \
        pk##i = (he << 16) | ho; }
    PKD(0)  PKD(1)  PKD(2)  PKD(3)  PKD(4)  PKD(5)  PKD(6)  PKD(7)
    PKD(8)  PKD(9)  PKD(10) PKD(11) PKD(12) PKD(13) PKD(14) PKD(15)
    PKD(16) PKD(17) PKD(18) PKD(19) PKD(20) PKD(21) PKD(22) PKD(23)
    PKD(24) PKD(25)
#undef PKD
    float w52 = __expf(trans[52 * CC + cc]);

    // ---- linear-domain forward: u = exp(alpha) * 2^-kexp ----
    float u = __expf(trans[BOS * CC + cc] + ep[1 * CC + cc]);
    int kexp = 0;   // uniform (SGPR)

    const float* epc = ep + cc;
    float pe0 = __expf(epc[(size_t)2 * CC]);
    float pe1 = __expf(epc[(size_t)3 * CC]);

#define FP(i, A, B) \
    A = fmaf(bcast_lane(u, 2*(i)),     __uint_as_float(pk##i & 0xffff0000u), A); \
    B = fmaf(bcast_lane(u, 2*(i) + 1), __uint_as_float(pk##i << 16),         B);

    for (int t = 2; t < len; ++t) {
        // Pin the 27 W regs in VGPRs: they are loop-carried through this
        // opaque asm (its outputs feed next iteration's inputs), so neither
        // spill-remat nor sinking can recompute them. r1-r4: VGPR_Count=40,
        // W lived in scratch/remat => ~825 stall cy/step.
        asm volatile("" :
            "+v"(pk0),  "+v"(pk1),  "+v"(pk2),  "+v"(pk3),  "+v"(pk4),
            "+v"(pk5),  "+v"(pk6),  "+v"(pk7),  "+v"(pk8),  "+v"(pk9),
            "+v"(pk10), "+v"(pk11), "+v"(pk12), "+v"(pk13), "+v"(pk14),
            "+v"(pk15), "+v"(pk16), "+v"(pk17), "+v"(pk18), "+v"(pk19),
            "+v"(pk20), "+v"(pk21), "+v"(pk22), "+v"(pk23), "+v"(pk24),
            "+v"(pk25), "+v"(w52));

        // off-critical-path renorm (all SALU): k = exponent of u[lane0]
        int ub = __builtin_amdgcn_readfirstlane((int)__float_as_uint(u));
        int k = ((ub >> 23) & 0xff) - 127;
        kexp += k;
        float pes = ldexpf(pe0, -k);          // v_ldexp_f32 v,v,s

        float a0 = 0.f, a1 = 0.f, a2 = 0.f, a3 = 0.f;
        FP(0,  a0, a1) FP(1,  a2, a3) FP(2,  a0, a1) FP(3,  a2, a3)
        FP(4,  a0, a1) FP(5,  a2, a3) FP(6,  a0, a1) FP(7,  a2, a3)
        FP(8,  a0, a1) FP(9,  a2, a3) FP(10, a0, a1) FP(11, a2, a3)
        FP(12, a0, a1) FP(13, a2, a3) FP(14, a0, a1) FP(15, a2, a3)
        FP(16, a0, a1) FP(17, a2, a3) FP(18, a0, a1) FP(19, a2, a3)
        FP(20, a0, a1) FP(21, a2, a3) FP(22, a0, a1) FP(23, a2, a3)
        FP(24, a0, a1) FP(25, a2, a3)
        a0 = fmaf(bcast_lane(u, 52), w52, a0);
        float acc = (a0 + a1) + (a2 + a3);    // > 0 always

        u = acc * pes;

        // rotate emission-prob pipeline (load t+2, clamped; 1-iter prefetch)
        pe0 = pe1;
        int tn = t + 2; tn = tn > TT - 1 ? TT - 1 : tn;
        pe1 = __expf(epc[(size_t)tn * CC]);
    }
#undef FP

    // ---- partition = log(sum_c u[c]*exp(T[c,EOS])) + kexp*ln2 ----
    float v = (lane < CC) ? u * __expf(trans[cc * CC + EOS]) : 0.f;
    #pragma unroll
    for (int o = 32; o > 0; o >>= 1) v += __shfl_xor(v, o);
    float logZ = __logf(v) + (float)kexp * 0.6931471805599453f;

    if (lane == 0) partial[b] = logZ - sc;
}

__global__ __launch_bounds__(256) void crf_reduce_kernel(
    const float* __restrict__ partial, float* __restrict__ out)
{
    float s = 0.f;
    #pragma unroll
    for (int k = 0; k < BB / 256; ++k) s += partial[threadIdx.x + 256 * k];
    #pragma unroll
    for (int o = 32; o > 0; o >>= 1) s += __shfl_xor(s, o);
    __shared__ float wsum[4];
    if ((threadIdx.x & 63) == 0) wsum[threadIdx.x >> 6] = s;
    __syncthreads();
    if (threadIdx.x == 0) out[0] = (wsum[0] + wsum[1]) + (wsum[2] + wsum[3]);
}

extern "C" void kernel_launch(void* const* d_in, const int* in_sizes, int n_in,
                              void* d_out, int out_size, void* d_ws, size_t ws_size,
                              hipStream_t stream) {
    const float* em    = (const float*)d_in[0];
    const int*   tags  = (const int*)d_in[1];
    const float* mask  = (const float*)d_in[2];
    const float* trans = (const float*)d_in[3];
    float* out = (float*)d_out;
    float* partial = (float*)d_ws;   // B floats of scratch

    crf_batch_kernel<<<BB, 64, 0, stream>>>(em, tags, mask, trans, partial);
    crf_reduce_kernel<<<1, 256, 0, stream>>>(partial, out);
}

// Round 8
// 252.829 us; speedup vs baseline: 1.4276x; 1.4276x over previous
//
#include <hip/hip_runtime.h>
#include <math.h>

#define BB 1024
#define TT 512
#define CC 53
#define BOS 1
#define EOS 2

__device__ __forceinline__ float bcast_lane(float x, int l) {
    return __uint_as_float(__builtin_amdgcn_readlane(__float_as_uint(x), l));
}

__global__ __launch_bounds__(64, 1) void crf_batch_kernel(
    const float* __restrict__ em,     // B,T,C
    const int*   __restrict__ tags,   // B,T
    const float* __restrict__ mask,   // B,T
    const float* __restrict__ trans,  // C,C
    float*       __restrict__ partial) // B  (partition - score)
{
    const int b = blockIdx.x;
    const int lane = threadIdx.x;             // 0..63
    const int cc = lane < CC ? lane : CC - 1; // lanes >= C mirror lane 52

    // ---- length = sum(mask[b,:]) ----
    const float* mrow = mask + (size_t)b * TT;
    float msum = 0.f;
    #pragma unroll
    for (int i = 0; i < TT / 64; ++i) msum += mrow[lane + 64 * i];
    #pragma unroll
    for (int o = 32; o > 0; o >>= 1) msum += __shfl_xor(msum, o);
    const int len = __builtin_amdgcn_readfirstlane((int)(msum + 0.5f)); // uniform

    // ---- score (gather part), lane-parallel over t ----
    const int* trow = tags + (size_t)b * TT;
    const float* ep = em + (size_t)b * TT * CC;
    float sc = 0.f;
    for (int t = 2 + lane; t < len; t += 64) {
        int tg = trow[t];
        int tp = trow[t - 1];
        sc += ep[(size_t)t * CC + tg] + trans[tp * CC + tg];
    }
    #pragma unroll
    for (int o = 32; o > 0; o >>= 1) sc += __shfl_xor(sc, o);
    if (lane == 0) {
        int t1 = trow[1];
        sc += trans[BOS * CC + t1] + ep[1 * CC + t1];   // "first"
        int tl = trow[len];
        sc += trans[tl * CC + EOS];                      // "last" (ref: tags[:, len])
    }

    // ---- W column: 53 named f32 regs, asm-pinned in the loop ----
#define WD(i) float w##i = __expf(trans[(i) * CC + cc]);
    WD(0)  WD(1)  WD(2)  WD(3)  WD(4)  WD(5)  WD(6)  WD(7)
    WD(8)  WD(9)  WD(10) WD(11) WD(12) WD(13) WD(14) WD(15)
    WD(16) WD(17) WD(18) WD(19) WD(20) WD(21) WD(22) WD(23)
    WD(24) WD(25) WD(26) WD(27) WD(28) WD(29) WD(30) WD(31)
    WD(32) WD(33) WD(34) WD(35) WD(36) WD(37) WD(38) WD(39)
    WD(40) WD(41) WD(42) WD(43) WD(44) WD(45) WD(46) WD(47)
    WD(48) WD(49) WD(50) WD(51) WD(52)
#undef WD

    // 30-operand asm limit: pin in two halves.
#define PINW() do { \
    asm volatile("" : \
        "+v"(w0),"+v"(w1),"+v"(w2),"+v"(w3),"+v"(w4),"+v"(w5),"+v"(w6), \
        "+v"(w7),"+v"(w8),"+v"(w9),"+v"(w10),"+v"(w11),"+v"(w12),"+v"(w13), \
        "+v"(w14),"+v"(w15),"+v"(w16),"+v"(w17),"+v"(w18),"+v"(w19),"+v"(w20), \
        "+v"(w21),"+v"(w22),"+v"(w23),"+v"(w24),"+v"(w25),"+v"(w26)); \
    asm volatile("" : \
        "+v"(w27),"+v"(w28),"+v"(w29),"+v"(w30),"+v"(w31),"+v"(w32),"+v"(w33), \
        "+v"(w34),"+v"(w35),"+v"(w36),"+v"(w37),"+v"(w38),"+v"(w39),"+v"(w40), \
        "+v"(w41),"+v"(w42),"+v"(w43),"+v"(w44),"+v"(w45),"+v"(w46),"+v"(w47), \
        "+v"(w48),"+v"(w49),"+v"(w50),"+v"(w51),"+v"(w52)); \
    } while (0)

#define F4(i0, i1, i2, i3) \
    a0 = fmaf(bcast_lane(u, i0), w##i0, a0); \
    a1 = fmaf(bcast_lane(u, i1), w##i1, a1); \
    a2 = fmaf(bcast_lane(u, i2), w##i2, a2); \
    a3 = fmaf(bcast_lane(u, i3), w##i3, a3);

#define MATVEC() \
    float a0 = 0.f, a1 = 0.f, a2 = 0.f, a3 = 0.f; \
    F4(0,1,2,3)     F4(4,5,6,7)     F4(8,9,10,11)   F4(12,13,14,15) \
    F4(16,17,18,19) F4(20,21,22,23) F4(24,25,26,27) F4(28,29,30,31) \
    F4(32,33,34,35) F4(36,37,38,39) F4(40,41,42,43) F4(44,45,46,47) \
    F4(48,49,50,51) \
    a0 = fmaf(bcast_lane(u, 52), w52, a0);

    // renorm: fold 2^-k (k = exponent of u[lane0]) into this step's pe
#define RENORM_PE(EV, PES) \
    int ub_ = __builtin_amdgcn_readfirstlane((int)__float_as_uint(u)); \
    int k_ = ((ub_ >> 23) & 0xff) - 127; kexp += k_; \
    float PES = ldexpf(__expf(EV), -k_);

    // step with renorm (every 4th) / plain step; each reloads its slot 8 ahead
#define STEP_RN(ES, OFF) { \
    RENORM_PE(ES, pes_) \
    MATVEC() \
    u = ((a0 + a1) + (a2 + a3)) * pes_; \
    int ii_ = t + (OFF); ii_ = ii_ > TT - 1 ? TT - 1 : ii_; \
    ES = epc[(size_t)ii_ * CC]; }

#define STEP_PL(ES, OFF) { \
    float pe_ = __expf(ES); \
    MATVEC() \
    u = ((a0 + a1) + (a2 + a3)) * pe_; \
    int ii_ = t + (OFF); ii_ = ii_ > TT - 1 ? TT - 1 : ii_; \
    ES = epc[(size_t)ii_ * CC]; }

    // ---- linear-domain forward: u = exp(alpha) * 2^-kexp ----
    float u = __expf(trans[BOS * CC + cc] + ep[1 * CC + cc]);
    int kexp = 0;
    const float* epc = ep + cc;

    // 8-deep RAW emission pipeline (exp deferred to consumption: first use of
    // each load is 8 steps (~1900 cy) later -> HBM ~900 cy latency hidden).
    // r1-r7 all applied expf in the load iteration => ~1 step slack => the
    // invariant ~1100 cy/step across 270-420 cy issue loads. len >= 256 > 9.
    float e0 = epc[(size_t)2 * CC], e1 = epc[(size_t)3 * CC];
    float e2 = epc[(size_t)4 * CC], e3 = epc[(size_t)5 * CC];
    float e4 = epc[(size_t)6 * CC], e5 = epc[(size_t)7 * CC];
    float e6 = epc[(size_t)8 * CC], e7 = epc[(size_t)9 * CC];

    int t = 2;
    for (; t + 8 <= len; t += 8) {
        PINW();
        STEP_RN(e0, 8)   STEP_PL(e1, 9)   STEP_PL(e2, 10)  STEP_PL(e3, 11)
        STEP_RN(e4, 12)  STEP_PL(e5, 13)  STEP_PL(e6, 14)  STEP_PL(e7, 15)
    }

    // tail: 0..7 steps, per-step renorm, slots in order e0..e6
    const int rem = len - t;
#define TAILSTEP(ES) { \
    RENORM_PE(ES, pes_) \
    MATVEC() \
    u = ((a0 + a1) + (a2 + a3)) * pes_; }
    if (rem > 0) TAILSTEP(e0)
    if (rem > 1) TAILSTEP(e1)
    if (rem > 2) TAILSTEP(e2)
    if (rem > 3) TAILSTEP(e3)
    if (rem > 4) TAILSTEP(e4)
    if (rem > 5) TAILSTEP(e5)
    if (rem > 6) TAILSTEP(e6)
#undef TAILSTEP
#undef STEP_PL
#undef STEP_RN
#undef RENORM_PE
#undef MATVEC
#undef F4
#undef PINW

    // ---- partition = log(sum_c u[c]*exp(T[c,EOS])) + kexp*ln2 ----
    float v = (lane < CC) ? u * __expf(trans[cc * CC + EOS]) : 0.f;
    #pragma unroll
    for (int o = 32; o > 0; o >>= 1) v += __shfl_xor(v, o);
    float logZ = __logf(v) + (float)kexp * 0.6931471805599453f;

    if (lane == 0) partial[b] = logZ - sc;
}

__global__ __launch_bounds__(256) void crf_reduce_kernel(
    const float* __restrict__ partial, float* __restrict__ out)
{
    float s = 0.f;
    #pragma unroll
    for (int k = 0; k < BB / 256; ++k) s += partial[threadIdx.x + 256 * k];
    #pragma unroll
    for (int o = 32; o > 0; o >>= 1) s += __shfl_xor(s, o);
    __shared__ float wsum[4];
    if ((threadIdx.x & 63) == 0) wsum[threadIdx.x >> 6] = s;
    __syncthreads();
    if (threadIdx.x == 0) out[0] = (wsum[0] + wsum[1]) + (wsum[2] + wsum[3]);
}

extern "C" void kernel_launch(void* const* d_in, const int* in_sizes, int n_in,
                              void* d_out, int out_size, void* d_ws, size_t ws_size,
                              hipStream_t stream) {
    const float* em    = (const float*)d_in[0];
    const int*   tags  = (const int*)d_in[1];
    const float* mask  = (const float*)d_in[2];
    const float* trans = (const float*)d_in[3];
    float* out = (float*)d_out;
    float* partial = (float*)d_ws;   // B floats of scratch

    crf_batch_kernel<<<BB, 64, 0, stream>>>(em, tags, mask, trans, partial);
    crf_reduce_kernel<<<1, 256, 0, stream>>>(partial, out);
}